// Round 12
// baseline (128.979 us; speedup 1.0000x reference)
//
#include <hip/hip_runtime.h>

// Minimax Conv2D, fused single kernel (R12).
// out[b,o,h,w] = min_p( max_q( patch[conn[o,3p+q]] - w1[o,3p+q] ) - w2[o,p] )
// Design: lane = pixel (4x16 tile), LDS row stride 24 -> exact 2-way banks (free).
// Per-channel constants (9 LDS-dword deltas + 9 w1 + 3 w2) live in LDS as a combined
// 24-dword/channel table built in-block before the barrier -> hot loop is a single
// in-order DS stream (broadcast table reads + gathers), no s_load, no SALU, no VMEM
// except the output stores. 48 KB LDS -> 3 blocks/CU x 8 waves = 75% occupancy.
// The kernel is launched TWICE (idempotent) to measure its time via dur_us delta.

#define IN_C  64
#define OUT_C 128
#define HH    64
#define WW    64
#define TH    4              // tile rows
#define TW    16             // tile cols
#define LR    (TH + 2)       // 6 rows incl. halo
#define LCV   (TW + 2)       // 18 valid cols incl. halo
#define LC    24             // padded row stride: banks exactly 2-way across the wave
#define CHS   (LR * LC)      // 144 dwords per channel
#define NTHR  512
#define TABS  24             // dwords per output channel in combined LDS table

__global__ __launch_bounds__(NTHR, 6)    // 6 waves/EU -> 3 blocks/CU, VGPR <= ~84
void mm_fused(const float* __restrict__ x,
              const float* __restrict__ w1,
              const float* __restrict__ w2,
              const int*   __restrict__ conn,
              float*       __restrict__ out) {
    __shared__ float xs[IN_C * CHS];          // 36864 B
    __shared__ int   tab[OUT_C * TABS];       // 12288 B  (int/float punned)

    const int tid = threadIdx.x;
    const int wt  = blockIdx.x;   // 0..3   (W tiles)
    const int ht  = blockIdx.y;   // 0..15  (H tiles)
    const int b   = blockIdx.z;   // 0..15  (batch)
    const int h0  = ht * TH;
    const int w0  = wt * TW;

    // ---- build combined per-channel table: [0..8]=delta, [9..17]=w1, [18..20]=w2 ----
    for (int i = tid; i < OUT_C * 9; i += NTHR) {
        const int o  = i / 9;
        const int t  = i - 9 * o;
        const int idx = conn[i];              // 0..575 = c*9 + kh*3 + kw
        const int c  = idx / 9;
        const int k  = idx - 9 * c;
        const int kh = k / 3;
        const int kw = k - 3 * kh;
        tab[o * TABS + t]     = c * CHS + kh * LC + kw;
        tab[o * TABS + 9 + t] = __float_as_int(w1[i]);
    }
    for (int i = tid; i < OUT_C * 3; i += NTHR) {
        const int o = i / 3;
        const int p = i - 3 * o;
        tab[o * TABS + 18 + p] = __float_as_int(w2[i]);
    }

    // ---- stage x tile (all 64 channels, replicate-clamped halo) ----
    const float* xb = x + (size_t)b * IN_C * HH * WW;
    for (int i = tid; i < IN_C * LR * LCV; i += NTHR) {
        int c  = i / (LR * LCV);
        int rm = i - c * (LR * LCV);
        int rr = rm / LCV;
        int cc = rm - rr * LCV;
        int gh = h0 + rr - 1; gh = gh < 0 ? 0 : (gh > HH - 1 ? HH - 1 : gh);
        int gw = w0 + cc - 1; gw = gw < 0 ? 0 : (gw > WW - 1 ? WW - 1 : gw);
        xs[c * CHS + rr * LC + cc] = xb[(c * HH + gh) * WW + gw];
    }
    __syncthreads();

    // ---- compute: wave owns 16 channels, lane owns 1 pixel ----
    const int lane = tid & 63;
    const int wid  = __builtin_amdgcn_readfirstlane(tid >> 6);  // 0..7, uniform
    const int r    = lane >> 4;    // 0..3
    const int cc   = lane & 15;    // 0..15
    const int base = r * LC + cc;  // pixel origin (dwords) in LDS tile

    float* op = out + ((((size_t)b * OUT_C + wid * 16) * HH) + (h0 + r)) * WW + (w0 + cc);

    #pragma unroll
    for (int oo = 0; oo < 16; ++oo) {
        const int o  = wid * 16 + oo;
        const int* tp = tab + o * TABS;       // uniform addr -> broadcast ds_read

        // table reads (broadcast) + gathers: one in-order DS stream
        int   dlt[9]; float w1v[9]; float w2v[3];
        #pragma unroll
        for (int t = 0; t < 9; ++t) dlt[t] = tp[t];
        #pragma unroll
        for (int t = 0; t < 9; ++t) w1v[t] = __int_as_float(tp[9 + t]);
        #pragma unroll
        for (int p = 0; p < 3; ++p) w2v[p] = __int_as_float(tp[18 + p]);

        float a[9];
        #pragma unroll
        for (int t = 0; t < 9; ++t) a[t] = xs[base + dlt[t]];

        float ma, mi;
        ma = a[0] - w1v[0];
        ma = fmaxf(ma, a[1] - w1v[1]);
        ma = fmaxf(ma, a[2] - w1v[2]);
        mi = ma - w2v[0];
        ma = a[3] - w1v[3];
        ma = fmaxf(ma, a[4] - w1v[4]);
        ma = fmaxf(ma, a[5] - w1v[5]);
        mi = fminf(mi, ma - w2v[1]);
        ma = a[6] - w1v[6];
        ma = fmaxf(ma, a[7] - w1v[7]);
        ma = fmaxf(ma, a[8] - w1v[8]);
        mi = fminf(mi, ma - w2v[2]);

        op[(size_t)oo * (HH * WW)] = mi;
    }
}

extern "C" void kernel_launch(void* const* d_in, const int* in_sizes, int n_in,
                              void* d_out, int out_size, void* d_ws, size_t ws_size,
                              hipStream_t stream) {
    const float* x    = (const float*)d_in[0];
    const float* w1   = (const float*)d_in[1];
    const float* w2   = (const float*)d_in[2];
    const int*   conn = (const int*)d_in[3];
    float*       out  = (float*)d_out;

    dim3 grid(WW / TW, HH / TH, 16);   // 4 x 16 x 16 = 1024 blocks
    // Launched twice (idempotent): dur_us delta vs single-launch baselines gives
    // the kernel's true time, independent of the ~68 us fixed harness overhead.
    mm_fused<<<grid, NTHR, 0, stream>>>(x, w1, w2, conn, out);
    mm_fused<<<grid, NTHR, 0, stream>>>(x, w1, w2, conn, out);
}

// Round 13
// 98.100 us; speedup vs baseline: 1.3148x; 1.3148x over previous
//
#include <hip/hip_runtime.h>

// Minimax Conv2D (R13): minimize LDS-pipe instructions per output.
// out[b,o,h,w] = min_p( max_q( patch[conn[o,3p+q]] - w1[o,3p+q] ) - w2[o,p] )
//
// The measured invariant across R6-R12 (~30 us) is LDS instruction issue:
// R12 = 30 DS instrs/wave-channel ~= 15.4K DS instrs/CU ~= 30+ us. This design:
//   - per-channel constants (9 deltas + 9 w1 + 3 w2, 24 dwords) in d_ws, read as
//     6x global_load_dwordx4 (VMEM/vmcnt, L1-resident) -> ZERO LDS table reads,
//     and no lgkmcnt coupling with gathers (table addr kept in VGPR via tid>>6).
//   - 2 pixels/lane (cc, cc+16) -> gathers merge to ds_read2_b32 offset1:16:
//     9 DS instrs per 2 outputs (4.5/output).
//   - LDS row stride 40: r*40 mod 32 = {0,8,16,24} -> exact 2-way banks (free).
// LDS instrs/CU ~2.7K (~7 us) < HBM floor (~10 us) -> HBM-bound target.

#define IN_C  64
#define OUT_C 128
#define HH    64
#define WW    64
#define TH    4              // tile rows
#define TW    32             // tile cols
#define LR    (TH + 2)       // 6 rows incl. halo
#define LCV   (TW + 2)       // 34 valid cols incl. halo
#define LC    40             // padded row stride (dwords)
#define CHS   (LR * LC)      // 240 dwords per channel
#define NTHR  512
#define TABS  24             // dwords per channel in combined table

__global__ __launch_bounds__(128)
void build_tab(const int* __restrict__ conn, const float* __restrict__ w1,
               const float* __restrict__ w2, int* __restrict__ tab) {
    const int o = threadIdx.x;          // one thread per output channel
    int*   tp = tab + o * TABS;
    float* fp = (float*)tp;
    #pragma unroll
    for (int t = 0; t < 9; ++t) {
        const int idx = conn[o * 9 + t];   // 0..575 = c*9 + kh*3 + kw
        const int c   = idx / 9;
        const int k   = idx - 9 * c;
        const int kh  = k / 3;
        const int kw  = k - 3 * kh;
        tp[t]     = c * CHS + kh * LC + kw;   // LDS dword delta
        fp[9 + t] = w1[o * 9 + t];
    }
    #pragma unroll
    for (int p = 0; p < 3; ++p) fp[18 + p] = w2[o * 3 + p];
    tp[21] = 0; tp[22] = 0; tp[23] = 0;
}

__global__ __launch_bounds__(NTHR, 4)   // 4 waves/EU -> 2 blocks/CU, VGPR <= 128
void mm_main(const float* __restrict__ x, const int* __restrict__ tab,
             float* __restrict__ out) {
    __shared__ float xs[IN_C * CHS];    // 61440 B -> exactly 2 blocks/CU

    const int tid = threadIdx.x;
    const int wt  = blockIdx.x;   // 0..1   (W tiles)
    const int ht  = blockIdx.y;   // 0..15  (H tiles)
    const int b   = blockIdx.z;   // 0..15  (batch)
    const int h0  = ht * TH;
    const int w0  = wt * TW;

    // ---- stage x tile (64 ch, replicate-clamped halo), stride 40 ----
    const float* xb = x + (size_t)b * IN_C * HH * WW;
    for (int i = tid; i < IN_C * LR * LCV; i += NTHR) {
        int c  = i / (LR * LCV);
        int rm = i - c * (LR * LCV);
        int rr = rm / LCV;
        int cc = rm - rr * LCV;
        int gh = h0 + rr - 1; gh = gh < 0 ? 0 : (gh > HH - 1 ? HH - 1 : gh);
        int gw = w0 + cc - 1; gw = gw < 0 ? 0 : (gw > WW - 1 ? WW - 1 : gw);
        xs[c * CHS + rr * LC + cc] = xb[(c * HH + gh) * WW + gw];
    }
    __syncthreads();

    // ---- compute: wave owns 16 channels; lane owns pixels (r,cc) and (r,cc+16) ----
    const int lane  = tid & 63;
    const int wid_v = tid >> 6;                                  // VGPR (forces VMEM table loads)
    const int wid   = __builtin_amdgcn_readfirstlane(wid_v);     // SGPR (store addressing)
    const int r     = lane >> 4;
    const int cc    = lane & 15;
    const int base  = r * LC + cc;

    // table base for this wave: single VGPR addr; per-channel access via imm offsets
    const int4* tw = (const int4*)(tab + wid_v * (16 * TABS));

    float* op = out + ((((size_t)b * OUT_C + wid * 16) * HH) + (h0 + r)) * WW + (w0 + cc);

    for (int oo = 0; oo < 16; oo += 2) {
        // ---- 12 VMEM table loads (L1-resident, vmcnt; no LDS pipe) ----
        const int4 I0 = tw[oo * 6 + 0];   // d0..d3
        const int4 I1 = tw[oo * 6 + 1];   // d4..d7
        const int4 I2 = tw[oo * 6 + 2];   // d8, w1_0..w1_2
        const int4 I3 = tw[oo * 6 + 3];   // w1_3..w1_6
        const int4 I4 = tw[oo * 6 + 4];   // w1_7, w1_8, w2_0, w2_1
        const int4 I5 = tw[oo * 6 + 5];   // w2_2, pad
        const int4 J0 = tw[oo * 6 + 6];
        const int4 J1 = tw[oo * 6 + 7];
        const int4 J2 = tw[oo * 6 + 8];
        const int4 J3 = tw[oo * 6 + 9];
        const int4 J4 = tw[oo * 6 + 10];
        const int4 J5 = tw[oo * 6 + 11];

        // ---- gathers: 9 ds_read2_b32 per channel (2 px each) ----
        float a0[9], a1[9], b0[9], b1[9];
        {
            const int d[9] = { I0.x, I0.y, I0.z, I0.w, I1.x, I1.y, I1.z, I1.w, I2.x };
            #pragma unroll
            for (int t = 0; t < 9; ++t) {
                const int ad = base + d[t];
                a0[t] = xs[ad];
                a1[t] = xs[ad + 16];
            }
        }
        {
            const int d[9] = { J0.x, J0.y, J0.z, J0.w, J1.x, J1.y, J1.z, J1.w, J2.x };
            #pragma unroll
            for (int t = 0; t < 9; ++t) {
                const int ad = base + d[t];
                b0[t] = xs[ad];
                b1[t] = xs[ad + 16];
            }
        }

        // ---- reduce channel oo ----
        const float w1a[9] = { __int_as_float(I2.y), __int_as_float(I2.z), __int_as_float(I2.w),
                               __int_as_float(I3.x), __int_as_float(I3.y), __int_as_float(I3.z),
                               __int_as_float(I3.w), __int_as_float(I4.x), __int_as_float(I4.y) };
        const float w2a[3] = { __int_as_float(I4.z), __int_as_float(I4.w), __int_as_float(I5.x) };
        const float w1b[9] = { __int_as_float(J2.y), __int_as_float(J2.z), __int_as_float(J2.w),
                               __int_as_float(J3.x), __int_as_float(J3.y), __int_as_float(J3.z),
                               __int_as_float(J3.w), __int_as_float(J4.x), __int_as_float(J4.y) };
        const float w2b[3] = { __int_as_float(J4.z), __int_as_float(J4.w), __int_as_float(J5.x) };

        #pragma unroll
        for (int px = 0; px < 2; ++px) {
            const float* a = px ? a1 : a0;
            float ma, mi;
            ma = a[0] - w1a[0];
            ma = fmaxf(ma, a[1] - w1a[1]);
            ma = fmaxf(ma, a[2] - w1a[2]);
            mi = ma - w2a[0];
            ma = a[3] - w1a[3];
            ma = fmaxf(ma, a[4] - w1a[4]);
            ma = fmaxf(ma, a[5] - w1a[5]);
            mi = fminf(mi, ma - w2a[1]);
            ma = a[6] - w1a[6];
            ma = fmaxf(ma, a[7] - w1a[7]);
            ma = fmaxf(ma, a[8] - w1a[8]);
            mi = fminf(mi, ma - w2a[2]);
            op[(size_t)oo * (HH * WW) + px * 16] = mi;
        }
        #pragma unroll
        for (int px = 0; px < 2; ++px) {
            const float* a = px ? b1 : b0;
            float ma, mi;
            ma = a[0] - w1b[0];
            ma = fmaxf(ma, a[1] - w1b[1]);
            ma = fmaxf(ma, a[2] - w1b[2]);
            mi = ma - w2b[0];
            ma = a[3] - w1b[3];
            ma = fmaxf(ma, a[4] - w1b[4]);
            ma = fmaxf(ma, a[5] - w1b[5]);
            mi = fminf(mi, ma - w2b[1]);
            ma = a[6] - w1b[6];
            ma = fmaxf(ma, a[7] - w1b[7]);
            ma = fmaxf(ma, a[8] - w1b[8]);
            mi = fminf(mi, ma - w2b[2]);
            op[(size_t)(oo + 1) * (HH * WW) + px * 16] = mi;
        }
    }
}

extern "C" void kernel_launch(void* const* d_in, const int* in_sizes, int n_in,
                              void* d_out, int out_size, void* d_ws, size_t ws_size,
                              hipStream_t stream) {
    const float* x    = (const float*)d_in[0];
    const float* w1   = (const float*)d_in[1];
    const float* w2   = (const float*)d_in[2];
    const int*   conn = (const int*)d_in[3];
    float*       out  = (float*)d_out;
    int*         tab  = (int*)d_ws;    // 128 * 24 dwords = 12 KB

    build_tab<<<1, 128, 0, stream>>>(conn, w1, w2, tab);

    dim3 grid(WW / TW, HH / TH, 16);   // 2 x 16 x 16 = 512 blocks (2 per CU)
    mm_main<<<grid, NTHR, 0, stream>>>(x, tab, out);
}